// Round 1
// baseline (273.500 us; speedup 1.0000x reference)
//
#include <hip/hip_runtime.h>
#include <hip/hip_bf16.h>

// y = x @ W^T where W is dense [N,N] but strictly diagonal.
// Exact equivalence: y[t,j] = x[t,j] * W[j,j]  (off-diag terms are exact 0.0f,
// adding exact zeros never changes an fp32 accumulator).
// Memory-bound elementwise scale: 128 MiB read + 128 MiB write -> ~42 us floor.

constexpr int N_FEAT  = 4096;           // IN_FEATURES
constexpr int TOKENS_ = 8192;
constexpr int NVEC_ROW = N_FEAT / 4;    // 1024 float4 per row
constexpr long TOTAL_VEC = (long)TOKENS_ * N_FEAT / 4;  // 8,388,608

__global__ __launch_bounds__(256)
void diag_scale_kernel(const float4* __restrict__ x,
                       const float*  __restrict__ W,
                       float4* __restrict__ y) {
    // Stage the diagonal into LDS (16 KiB). Strided global reads (stride
    // N_FEAT+1 floats) — L2-resident after the first blocks touch them.
    __shared__ float4 sdiag[NVEC_ROW];
    float* sd = reinterpret_cast<float*>(sdiag);
    for (int j = threadIdx.x; j < N_FEAT; j += 256) {
        sd[j] = W[(long)j * (N_FEAT + 1)];
    }
    __syncthreads();

    const long stride = (long)gridDim.x * 256;
    for (long i = (long)blockIdx.x * 256 + threadIdx.x; i < TOTAL_VEC; i += stride) {
        float4 xv = x[i];
        float4 dv = sdiag[(int)(i & (NVEC_ROW - 1))];
        float4 o;
        o.x = xv.x * dv.x;
        o.y = xv.y * dv.y;
        o.z = xv.z * dv.z;
        o.w = xv.w * dv.w;
        y[i] = o;
    }
}

extern "C" void kernel_launch(void* const* d_in, const int* in_sizes, int n_in,
                              void* d_out, int out_size, void* d_ws, size_t ws_size,
                              hipStream_t stream) {
    const float4* x = (const float4*)d_in[0];   // [8192, 4096] f32
    const float*  W = (const float*)d_in[1];    // [4096, 4096] f32, diagonal
    float4* y = (float4*)d_out;                 // [8192, 4096] f32

    // 2048 blocks = 8 blocks/CU on 256 CUs; each thread handles 16 float4s.
    diag_scale_kernel<<<2048, 256, 0, stream>>>(x, W, y);
}